// Round 2
// baseline (3799.043 us; speedup 1.0000x reference)
//
#include <hip/hip_runtime.h>
#include <math.h>

#define MR_C     256
#define MR_L     8192
#define MR_DEPTH 12
#define TPB      1024
// each thread owns 2 float4 groups, strided TPB apart (coalesced)

__device__ __forceinline__ float4 f4z() { return make_float4(0.f, 0.f, 0.f, 0.f); }

// One level-step for one float4 group. LEV folds the dilation at compile time.
// - res_lo is re-read from LDS (bc[g]): identical to last level's store, saves
//   8 persistent VGPRs vs carrying it in registers.
// - wi is pre-folded into G1 = wi*F1 so acc accumulates with direct FMAs and
//   the `hi` float4 temp disappears (-4 regs in flight per group).
template<int LEV>
__device__ __forceinline__ float4 level_group(
    int g, float4& acc,
    const float4* __restrict__ bc,
    const float4 F0, const float4 G1)
{
    constexpr int d = 1 << LEV;
    const float4 rl = bc[g];
    float4 t1, t2, t3;   // taps at t-d, t-2d, t-3d

    if constexpr (d == 1) {
        float4 p = (g >= 1) ? bc[g - 1] : f4z();
        t1 = make_float4(p.w, rl.x, rl.y, rl.z);
        t2 = make_float4(p.z, p.w, rl.x, rl.y);
        t3 = make_float4(p.y, p.z, p.w, rl.x);
    } else if constexpr (d == 2) {
        float4 p  = (g >= 1) ? bc[g - 1] : f4z();
        float4 p2 = (g >= 2) ? bc[g - 2] : f4z();
        t1 = make_float4(p.z, p.w, rl.x, rl.y);
        t2 = p;
        t3 = make_float4(p2.z, p2.w, p.x, p.y);
    } else {
        constexpr int d4 = d >> 2;   // d % 4 == 0: aligned float4 taps
        t1 = (g >= d4)     ? bc[g - d4]     : f4z();
        t2 = (g >= 2 * d4) ? bc[g - 2 * d4] : f4z();
        t3 = (g >= 3 * d4) ? bc[g - 3 * d4] : f4z();
    }

    // coefficient of x[t - d*j] is h[3-j]
    // y-accumulation: acc += wi*(F1.w*rl + F1.z*t1 + F1.y*t2 + F1.x*t3), wi folded into G1
    acc.x += G1.w * rl.x + G1.z * t1.x + G1.y * t2.x + G1.x * t3.x;
    acc.y += G1.w * rl.y + G1.z * t1.y + G1.y * t2.y + G1.x * t3.y;
    acc.z += G1.w * rl.z + G1.z * t1.z + G1.y * t2.z + G1.x * t3.z;
    acc.w += G1.w * rl.w + G1.z * t1.w + G1.y * t2.w + G1.x * t3.w;

    float4 nl;
    nl.x = F0.w * rl.x + F0.z * t1.x + F0.y * t2.x + F0.x * t3.x;
    nl.y = F0.w * rl.y + F0.z * t1.y + F0.y * t2.y + F0.x * t3.y;
    nl.z = F0.w * rl.z + F0.z * t1.z + F0.y * t2.z + F0.x * t3.z;
    nl.w = F0.w * rl.w + F0.z * t1.w + F0.y * t2.w + F0.x * t3.w;

    return nl;
}

// R4 THEORY: 64-VGPR budget is LDS-occupancy-derived (64KiB LDS -> 2 blk/CU ->
// 8 waves/EU -> 512/8 = 64) and attributes don't lower that target. Instead of
// raising the cap, FIT in 64: sched_barrier(0) between the two per-thread
// groups stops the scheduler from interleaving both groups' tap-loads+FMA
// chains (peak was ~28 persistent + 2x22 temps > 64 -> ~25 slots spilled ->
// 9 GB scratch round-trip = the whole runtime). With separation: ~28 + 20 < 64,
// zero spills, and we KEEP the 2-blocks/CU 8-waves/EU operating point.
__global__ __launch_bounds__(TPB) void multires_fused(
    const float* __restrict__ x,
    const float* __restrict__ h0,
    const float* __restrict__ h1,
    const float* __restrict__ w,
    float* __restrict__ out)
{
    __shared__ float4 buf0[MR_L / 4];
    __shared__ float4 buf1[MR_L / 4];

    const int row = blockIdx.x;            // b*C + c
    const int c   = row & (MR_C - 1);
    const int tid = threadIdx.x;

    // block-uniform filter/weight loads (scalar path, L2-cached)
    const float4 F0 = ((const float4*)h0)[c];
    const float4 F1 = ((const float4*)h1)[c];
    const float* __restrict__ wrow = w + c * (MR_DEPTH + 2);
    const float wlast = wrow[MR_DEPTH + 1];

    const float4* __restrict__ xrow = (const float4*)(x + (size_t)row * MR_L);
    const int g0 = tid, g1 = tid + TPB;

    float4 v0 = xrow[g0], v1 = xrow[g1];
    float4 acc0, acc1;
    acc0.x = v0.x * wlast; acc0.y = v0.y * wlast; acc0.z = v0.z * wlast; acc0.w = v0.w * wlast;
    acc1.x = v1.x * wlast; acc1.y = v1.y * wlast; acc1.z = v1.z * wlast; acc1.w = v1.w * wlast;
    buf0[g0] = v0; buf0[g1] = v1;
    __syncthreads();

    const float4* bc = buf0;
    float4*       bn = buf1;

    float4 nl0, nl1;   // after DO_LEVEL(11): final res_lo

#define DO_LEVEL(LEV)                                                          \
    {                                                                          \
        const float wi = wrow[MR_DEPTH - (LEV)];                               \
        float4 G1;                                                             \
        G1.x = wi * F1.x; G1.y = wi * F1.y; G1.z = wi * F1.z; G1.w = wi * F1.w;\
        nl0 = level_group<LEV>(g0, acc0, bc, F0, G1);                          \
        __builtin_amdgcn_sched_barrier(0);                                     \
        nl1 = level_group<LEV>(g1, acc1, bc, F0, G1);                          \
        if ((LEV) != MR_DEPTH - 1) {                                           \
            bn[g0] = nl0; bn[g1] = nl1;                                        \
            __syncthreads();                                                   \
        }                                                                      \
        const float4* tswap = bn; bn = (float4*)bc; bc = tswap;                \
    }

    DO_LEVEL(0)  DO_LEVEL(1)  DO_LEVEL(2)  DO_LEVEL(3)
    DO_LEVEL(4)  DO_LEVEL(5)  DO_LEVEL(6)  DO_LEVEL(7)
    DO_LEVEL(8)  DO_LEVEL(9)  DO_LEVEL(10) DO_LEVEL(11)
#undef DO_LEVEL

    // epilogue: y += w[:,0] * res_lo; exact-erf GELU; coalesced float4 store.
    // Group 0 fully retired (computed+stored) before group 1 starts: keeps
    // epilogue pressure low too.
    float4* __restrict__ orow = (float4*)(out + (size_t)row * MR_L);
    const float w0 = wrow[0];
    const float inv_sqrt2 = 0.70710678118654752f;

    {
        float4 v; float u;
        u = acc0.x + w0 * nl0.x; v.x = 0.5f * u * (1.0f + erff(u * inv_sqrt2));
        u = acc0.y + w0 * nl0.y; v.y = 0.5f * u * (1.0f + erff(u * inv_sqrt2));
        u = acc0.z + w0 * nl0.z; v.z = 0.5f * u * (1.0f + erff(u * inv_sqrt2));
        u = acc0.w + w0 * nl0.w; v.w = 0.5f * u * (1.0f + erff(u * inv_sqrt2));
        orow[g0] = v;
    }
    __builtin_amdgcn_sched_barrier(0);
    {
        float4 v; float u;
        u = acc1.x + w0 * nl1.x; v.x = 0.5f * u * (1.0f + erff(u * inv_sqrt2));
        u = acc1.y + w0 * nl1.y; v.y = 0.5f * u * (1.0f + erff(u * inv_sqrt2));
        u = acc1.z + w0 * nl1.z; v.z = 0.5f * u * (1.0f + erff(u * inv_sqrt2));
        u = acc1.w + w0 * nl1.w; v.w = 0.5f * u * (1.0f + erff(u * inv_sqrt2));
        orow[g1] = v;
    }
}

extern "C" void kernel_launch(void* const* d_in, const int* in_sizes, int n_in,
                              void* d_out, int out_size, void* d_ws, size_t ws_size,
                              hipStream_t stream) {
    const float* x  = (const float*)d_in[0];
    const float* h0 = (const float*)d_in[1];
    const float* h1 = (const float*)d_in[2];
    const float* w  = (const float*)d_in[3];
    float* o        = (float*)d_out;

    const int rows = in_sizes[0] / MR_L;   // B*C = 4096
    multires_fused<<<rows, TPB, 0, stream>>>(x, h0, h1, w, o);
}